// Round 1
// baseline (1050.957 us; speedup 1.0000x reference)
//
#include <hip/hip_runtime.h>
#include <hip/hip_bf16.h>
#include <math.h>

namespace {

constexpr int Dm  = 2048;
constexpr int FFm = 8192;
constexpr int SEQ = 2048;
constexpr int HDm = 128;
constexpr int MR  = 4096;     // B*S
constexpr int QW  = 3 * Dm;   // 6144

typedef __bf16 bf16_t;
typedef __bf16 bf16x8 __attribute__((ext_vector_type(8)));
typedef float  f32x4  __attribute__((ext_vector_type(4)));

typedef __attribute__((address_space(1))) const void as1_void;
typedef __attribute__((address_space(3))) void as3_void;

__device__ __forceinline__ void gload_lds16(const void* g, void* l) {
  __builtin_amdgcn_global_load_lds((as1_void*)g, (as3_void*)l, 16, 0, 0);
}

// ---------------- LayerNorm: fp32 in -> bf16 out ----------------
__global__ __launch_bounds__(256)
void ln_kernel(const float* __restrict__ x, const float* __restrict__ sc,
               const float* __restrict__ sh, bf16_t* __restrict__ out)
{
  const int row = blockIdx.x;
  const int tid = threadIdx.x;
  const float4* xr = (const float4*)(x + (size_t)row * Dm);
  float4 v0 = xr[tid*2], v1 = xr[tid*2+1];
  float s  = v0.x+v0.y+v0.z+v0.w + v1.x+v1.y+v1.z+v1.w;
  float s2 = v0.x*v0.x+v0.y*v0.y+v0.z*v0.z+v0.w*v0.w
           + v1.x*v1.x+v1.y*v1.y+v1.z*v1.z+v1.w*v1.w;
  #pragma unroll
  for (int off = 32; off; off >>= 1) { s += __shfl_xor(s, off); s2 += __shfl_xor(s2, off); }
  __shared__ float red[8];
  if ((tid & 63) == 0) { red[(tid>>6)*2] = s; red[(tid>>6)*2+1] = s2; }
  __syncthreads();
  s  = red[0]+red[2]+red[4]+red[6];
  s2 = red[1]+red[3]+red[5]+red[7];
  const float mean = s * (1.f/Dm);
  const float var  = fmaxf(s2 * (1.f/Dm) - mean*mean, 0.f);
  const float rstd = rsqrtf(var + 1e-5f);
  const float4* scp = (const float4*)sc;
  const float4* shp = (const float4*)sh;
  float4 sc0 = scp[tid*2], sc1 = scp[tid*2+1];
  float4 sh0 = shp[tid*2], sh1 = shp[tid*2+1];
  __attribute__((aligned(16))) bf16_t ob[8];
  ob[0] = (bf16_t)((v0.x-mean)*rstd*sc0.x + sh0.x);
  ob[1] = (bf16_t)((v0.y-mean)*rstd*sc0.y + sh0.y);
  ob[2] = (bf16_t)((v0.z-mean)*rstd*sc0.z + sh0.z);
  ob[3] = (bf16_t)((v0.w-mean)*rstd*sc0.w + sh0.w);
  ob[4] = (bf16_t)((v1.x-mean)*rstd*sc1.x + sh1.x);
  ob[5] = (bf16_t)((v1.y-mean)*rstd*sc1.y + sh1.y);
  ob[6] = (bf16_t)((v1.z-mean)*rstd*sc1.z + sh1.z);
  ob[7] = (bf16_t)((v1.w-mean)*rstd*sc1.w + sh1.w);
  *(uint4*)(out + (size_t)row*Dm + tid*8) = *(const uint4*)ob;
}

// ------------- weight fp32 [K][N] -> bf16 transposed [N][K] -------------
__global__ __launch_bounds__(256)
void wconv_t(const float* __restrict__ W, bf16_t* __restrict__ WT, int K, int N)
{
  __shared__ float tile[32][33];
  const int tx = threadIdx.x & 31, ty = threadIdx.x >> 5;
  const int nb = blockIdx.x * 32, kb = blockIdx.y * 32;
  #pragma unroll
  for (int p = 0; p < 4; ++p)
    tile[ty+8*p][tx] = W[(size_t)(kb+ty+8*p)*N + nb + tx];
  __syncthreads();
  #pragma unroll
  for (int p = 0; p < 4; ++p)
    WT[(size_t)(nb+ty+8*p)*K + kb + tx] = (bf16_t)tile[tx][ty+8*p];
}

__global__ void bias_concat(const float* __restrict__ bq, const float* __restrict__ bk,
                            const float* __restrict__ bv, float* __restrict__ o)
{
  int i = blockIdx.x*256 + threadIdx.x;
  o[i] = bq[i]; o[Dm+i] = bk[i]; o[2*Dm+i] = bv[i];
}

// ----- V slice of qkv [B*S][6144] -> vT [B*H][128][2048] (bf16) -----
__global__ __launch_bounds__(256)
void vtrans(const bf16_t* __restrict__ qkv, bf16_t* __restrict__ vT)
{
  __shared__ bf16_t tile[32][33];
  const int tx = threadIdx.x & 31, ty = threadIdx.x >> 5;
  const int s0 = blockIdx.x*32, d0 = blockIdx.y*32, bh = blockIdx.z;
  const int b = bh >> 4, h = bh & 15;
  const bf16_t* src = qkv + (size_t)(b*SEQ)*QW + 2*Dm + h*HDm;
  #pragma unroll
  for (int p = 0; p < 4; ++p)
    tile[ty+8*p][tx] = src[(size_t)(s0+ty+8*p)*QW + d0 + tx];
  __syncthreads();
  bf16_t* dst = vT + (size_t)bh*HDm*SEQ;
  #pragma unroll
  for (int p = 0; p < 4; ++p)
    dst[(size_t)(d0+ty+8*p)*SEQ + s0 + tx] = tile[tx][ty+8*p];
}

// ------- GEMM: C[M,N] = act(A[M,K] @ BT[N,K]^T + bias) (+resid) -------
// m97 structure: 128x128 tile, BK=32, 4 waves (2x2), global_load_lds x16.
template<bool OUT_BF16, bool GELU_, bool RESID>
__global__ __launch_bounds__(256)
void gemm_bt(const bf16_t* __restrict__ A, const bf16_t* __restrict__ BT,
             const float* __restrict__ bias, const float* __restrict__ resid,
             void* __restrict__ Cout, int Ndim, int Kdim)
{
  const int n0 = blockIdx.x * 128;
  const int m0 = blockIdx.y * 128;
  const int tid = threadIdx.x;
  const int lane = tid & 63;
  const int wid = tid >> 6;
  const int wr = wid >> 1, wc = wid & 1;
  const int lr = lane & 15, kg = lane >> 4;

  __shared__ __attribute__((aligned(16))) bf16_t As[128*32];
  __shared__ __attribute__((aligned(16))) bf16_t Bs[128*32];

  f32x4 acc[4][4] = {};

  const int ia = tid, ib = tid + 256;
  const bf16_t* gA0 = A  + (size_t)(m0 + (ia>>2))*Kdim + (ia&3)*8;
  const bf16_t* gA1 = A  + (size_t)(m0 + (ib>>2))*Kdim + (ib&3)*8;
  const bf16_t* gB0 = BT + (size_t)(n0 + (ia>>2))*Kdim + (ia&3)*8;
  const bf16_t* gB1 = BT + (size_t)(n0 + (ib>>2))*Kdim + (ib&3)*8;
  bf16_t* lA0 = As + ia*8; bf16_t* lA1 = As + ib*8;
  bf16_t* lB0 = Bs + ia*8; bf16_t* lB1 = Bs + ib*8;

  for (int k0 = 0; k0 < Kdim; k0 += 32) {
    gload_lds16(gA0 + k0, lA0);
    gload_lds16(gA1 + k0, lA1);
    gload_lds16(gB0 + k0, lB0);
    gload_lds16(gB1 + k0, lB1);
    __syncthreads();
    bf16x8 af[4], bfr[4];
    #pragma unroll
    for (int m = 0; m < 4; ++m)
      af[m] = *(const bf16x8*)(As + (wr*64 + m*16 + lr)*32 + kg*8);
    #pragma unroll
    for (int n = 0; n < 4; ++n)
      bfr[n] = *(const bf16x8*)(Bs + (wc*64 + n*16 + lr)*32 + kg*8);
    #pragma unroll
    for (int m = 0; m < 4; ++m)
      #pragma unroll
      for (int n = 0; n < 4; ++n)
        acc[m][n] = __builtin_amdgcn_mfma_f32_16x16x32_bf16(af[m], bfr[n], acc[m][n], 0, 0, 0);
    __syncthreads();
  }

  const int cr0 = m0 + wr*64 + kg*4;
  #pragma unroll
  for (int n = 0; n < 4; ++n) {
    const int col = n0 + wc*64 + n*16 + lr;
    const float bv = bias[col];
    #pragma unroll
    for (int m = 0; m < 4; ++m) {
      const int rbase = cr0 + m*16;
      #pragma unroll
      for (int j = 0; j < 4; ++j) {
        float v = acc[m][n][j] + bv;
        if constexpr (GELU_) v = 0.5f*v*(1.f + erff(v*0.70710678118f));
        size_t idx = (size_t)(rbase + j)*Ndim + col;
        if constexpr (RESID) v += resid[idx];
        if constexpr (OUT_BF16) ((bf16_t*)Cout)[idx] = (bf16_t)v;
        else ((float*)Cout)[idx] = v;
      }
    }
  }
}

// ---------------- causal flash attention ----------------
// 1 wave per (bh, 16 q-rows). Q in regs, K from qkv, V from vT, KBLK=32.
__global__ __launch_bounds__(64)
void flash_attn(const bf16_t* __restrict__ qkv, const bf16_t* __restrict__ vT,
                bf16_t* __restrict__ ctx)
{
  const int qt = blockIdx.x & 127;     // S/16
  const int bh = blockIdx.x >> 7;      // 0..31
  const int b = bh >> 4, h = bh & 15;
  const int q0 = qt * 16;
  const int lane = threadIdx.x;
  const int lr = lane & 15, kg = lane >> 4;

  __shared__ __attribute__((aligned(16))) bf16_t Plds[16*32];

  const bf16_t* qbase = qkv + (size_t)(b*SEQ + q0 + lr)*QW + h*HDm;
  bf16x8 qf[4];
  #pragma unroll
  for (int t = 0; t < 4; ++t)
    qf[t] = *(const bf16x8*)(qbase + t*32 + kg*8);

  const float scl = 0.08838834764831845f * 1.44269504089f; // 1/sqrt(128)*log2(e)
  float mrow[4], lsum[4];
  f32x4 oacc[8];
  #pragma unroll
  for (int j = 0; j < 4; ++j) { mrow[j] = -INFINITY; lsum[j] = 0.f; }
  #pragma unroll
  for (int t = 0; t < 8; ++t) oacc[t] = (f32x4){0.f, 0.f, 0.f, 0.f};

  const bf16_t* kbase = qkv + (size_t)(b*SEQ)*QW + Dm + h*HDm;
  const bf16_t* vbase = vT + (size_t)bh*HDm*SEQ;

  const int nsteps = (q0 + 16 + 31) >> 5;
  for (int t = 0; t < nsteps; ++t) {
    const int k0 = t*32;
    f32x4 sa[2] = {{0,0,0,0},{0,0,0,0}};
    #pragma unroll
    for (int ct = 0; ct < 2; ++ct) {
      const bf16_t* kb = kbase + (size_t)(k0 + ct*16 + lr)*QW + kg*8;
      #pragma unroll
      for (int g4 = 0; g4 < 4; ++g4) {
        bf16x8 kf = *(const bf16x8*)(kb + g4*32);
        sa[ct] = __builtin_amdgcn_mfma_f32_16x16x32_bf16(qf[g4], kf, sa[ct], 0, 0, 0);
      }
    }
    float sl[2][4];
    #pragma unroll
    for (int ct = 0; ct < 2; ++ct)
      #pragma unroll
      for (int j = 0; j < 4; ++j) sl[ct][j] = sa[ct][j] * scl;
    if (k0 + 31 > q0) {
      #pragma unroll
      for (int ct = 0; ct < 2; ++ct) {
        const int kidx = k0 + ct*16 + lr;
        #pragma unroll
        for (int j = 0; j < 4; ++j) {
          const int qidx = q0 + kg*4 + j;
          if (kidx > qidx) sl[ct][j] = -INFINITY;
        }
      }
    }
    float alpha[4], p0[4], p1[4];
    #pragma unroll
    for (int j = 0; j < 4; ++j) {
      float v = fmaxf(sl[0][j], sl[1][j]);
      v = fmaxf(v, __shfl_xor(v, 1));
      v = fmaxf(v, __shfl_xor(v, 2));
      v = fmaxf(v, __shfl_xor(v, 4));
      v = fmaxf(v, __shfl_xor(v, 8));
      const float mn = fmaxf(mrow[j], v);
      alpha[j] = exp2f(mrow[j] - mn);
      mrow[j] = mn;
      p0[j] = exp2f(sl[0][j] - mn);
      p1[j] = exp2f(sl[1][j] - mn);
      float s = p0[j] + p1[j];
      s += __shfl_xor(s, 1);
      s += __shfl_xor(s, 2);
      s += __shfl_xor(s, 4);
      s += __shfl_xor(s, 8);
      lsum[j] = lsum[j]*alpha[j] + s;
    }
    #pragma unroll
    for (int dt = 0; dt < 8; ++dt)
      #pragma unroll
      for (int j = 0; j < 4; ++j) oacc[dt][j] *= alpha[j];
    #pragma unroll
    for (int j = 0; j < 4; ++j) {
      Plds[(kg*4+j)*32 + lr]      = (bf16_t)p0[j];
      Plds[(kg*4+j)*32 + 16 + lr] = (bf16_t)p1[j];
    }
    __syncthreads();
    bf16x8 pf = *(const bf16x8*)(Plds + lr*32 + kg*8);
    #pragma unroll
    for (int dt = 0; dt < 8; ++dt) {
      bf16x8 vf = *(const bf16x8*)(vbase + (size_t)(dt*16 + lr)*SEQ + k0 + kg*8);
      oacc[dt] = __builtin_amdgcn_mfma_f32_16x16x32_bf16(pf, vf, oacc[dt], 0, 0, 0);
    }
    __syncthreads();
  }

  bf16_t* cb = ctx + (size_t)(b*SEQ + q0 + kg*4)*Dm + h*HDm;
  #pragma unroll
  for (int j = 0; j < 4; ++j) {
    const float inv = 1.f / lsum[j];
    #pragma unroll
    for (int dt = 0; dt < 8; ++dt)
      cb[(size_t)j*Dm + dt*16 + lr] = (bf16_t)(oacc[dt][j] * inv);
  }
}

} // namespace

extern "C" void kernel_launch(void* const* d_in, const int* in_sizes, int n_in,
                              void* d_out, int out_size, void* d_ws, size_t ws_size,
                              hipStream_t stream)
{
  const float* x   = (const float*)d_in[0];
  const float* g1  = (const float*)d_in[1];
  const float* s1  = (const float*)d_in[2];
  const float* wq  = (const float*)d_in[3];
  const float* bq  = (const float*)d_in[4];
  const float* wk  = (const float*)d_in[5];
  const float* bk  = (const float*)d_in[6];
  const float* wv  = (const float*)d_in[7];
  const float* bv  = (const float*)d_in[8];
  const float* wo  = (const float*)d_in[9];
  const float* bo  = (const float*)d_in[10];
  const float* g2  = (const float*)d_in[11];
  const float* s2  = (const float*)d_in[12];
  const float* w1  = (const float*)d_in[13];
  const float* b1  = (const float*)d_in[14];
  const float* w2  = (const float*)d_in[15];
  const float* b2  = (const float*)d_in[16];
  float* out = (float*)d_out;

  char* p = (char*)d_ws;
  bf16_t* wqkvT = (bf16_t*)p;  p += (size_t)QW*Dm*2;
  bf16_t* woT   = (bf16_t*)p;  p += (size_t)Dm*Dm*2;
  bf16_t* w1T   = (bf16_t*)p;  p += (size_t)FFm*Dm*2;
  bf16_t* w2T   = (bf16_t*)p;  p += (size_t)Dm*FFm*2;
  float*  bqkv  = (float*)p;   p += (size_t)QW*4;
  bf16_t* hbuf  = (bf16_t*)p;  p += (size_t)MR*Dm*2;
  bf16_t* qkv   = (bf16_t*)p;  p += (size_t)MR*QW*2;
  bf16_t* vTb   = (bf16_t*)p;  p += (size_t)32*HDm*SEQ*2;
  bf16_t* ctx   = (bf16_t*)p;  p += (size_t)MR*Dm*2;
  float*  x1    = (float*)p;   p += (size_t)MR*Dm*4;
  bf16_t* ffn1  = qkv;  // reuse qkv+vT+ctx region (29.4M+8.4M elems >= 33.6M)

  wconv_t<<<dim3(Dm/32, Dm/32), 256, 0, stream>>>(wq, wqkvT, Dm, Dm);
  wconv_t<<<dim3(Dm/32, Dm/32), 256, 0, stream>>>(wk, wqkvT + (size_t)Dm*Dm, Dm, Dm);
  wconv_t<<<dim3(Dm/32, Dm/32), 256, 0, stream>>>(wv, wqkvT + (size_t)2*Dm*Dm, Dm, Dm);
  wconv_t<<<dim3(Dm/32, Dm/32), 256, 0, stream>>>(wo, woT, Dm, Dm);
  wconv_t<<<dim3(FFm/32, Dm/32), 256, 0, stream>>>(w1, w1T, Dm, FFm);
  wconv_t<<<dim3(Dm/32, FFm/32), 256, 0, stream>>>(w2, w2T, FFm, Dm);
  bias_concat<<<dim3(Dm/256), 256, 0, stream>>>(bq, bk, bv, bqkv);

  ln_kernel<<<dim3(MR), 256, 0, stream>>>(x, g1, s1, hbuf);
  gemm_bt<true,false,false><<<dim3(QW/128, MR/128), 256, 0, stream>>>(
      hbuf, wqkvT, bqkv, nullptr, qkv, QW, Dm);
  vtrans<<<dim3(SEQ/32, HDm/32, 32), 256, 0, stream>>>(qkv, vTb);
  flash_attn<<<dim3(32*(SEQ/16)), 64, 0, stream>>>(qkv, vTb, ctx);
  gemm_bt<false,false,true><<<dim3(Dm/128, MR/128), 256, 0, stream>>>(
      ctx, woT, bo, x, x1, Dm, Dm);
  ln_kernel<<<dim3(MR), 256, 0, stream>>>(x1, g2, s2, hbuf);
  gemm_bt<true,true,false><<<dim3(FFm/128, MR/128), 256, 0, stream>>>(
      hbuf, w1T, b1, nullptr, ffn1, FFm, Dm);
  gemm_bt<false,false,true><<<dim3(Dm/128, MR/128), 256, 0, stream>>>(
      ffn1, w2T, b2, x1, out, Dm, FFm);
}

// Round 2
// 992.944 us; speedup vs baseline: 1.0584x; 1.0584x over previous
//
#include <hip/hip_runtime.h>
#include <hip/hip_bf16.h>
#include <math.h>

namespace {

constexpr int Dm  = 2048;
constexpr int FFm = 8192;
constexpr int SEQ = 2048;
constexpr int HDm = 128;
constexpr int MR  = 4096;     // B*S
constexpr int QW  = 3 * Dm;   // 6144

typedef __bf16 bf16_t;
typedef __bf16 bf16x8 __attribute__((ext_vector_type(8)));
typedef float  f32x4  __attribute__((ext_vector_type(4)));

typedef __attribute__((address_space(1))) const void as1_void;
typedef __attribute__((address_space(3))) void as3_void;

__device__ __forceinline__ void gload_lds16(const void* g, void* l) {
  __builtin_amdgcn_global_load_lds((as1_void*)g, (as3_void*)l, 16, 0, 0);
}

// ---------------- LayerNorm: fp32 in -> bf16 out ----------------
__global__ __launch_bounds__(256)
void ln_kernel(const float* __restrict__ x, const float* __restrict__ sc,
               const float* __restrict__ sh, bf16_t* __restrict__ out)
{
  const int row = blockIdx.x;
  const int tid = threadIdx.x;
  const float4* xr = (const float4*)(x + (size_t)row * Dm);
  float4 v0 = xr[tid*2], v1 = xr[tid*2+1];
  float s  = v0.x+v0.y+v0.z+v0.w + v1.x+v1.y+v1.z+v1.w;
  float s2 = v0.x*v0.x+v0.y*v0.y+v0.z*v0.z+v0.w*v0.w
           + v1.x*v1.x+v1.y*v1.y+v1.z*v1.z+v1.w*v1.w;
  #pragma unroll
  for (int off = 32; off; off >>= 1) { s += __shfl_xor(s, off); s2 += __shfl_xor(s2, off); }
  __shared__ float red[8];
  if ((tid & 63) == 0) { red[(tid>>6)*2] = s; red[(tid>>6)*2+1] = s2; }
  __syncthreads();
  s  = red[0]+red[2]+red[4]+red[6];
  s2 = red[1]+red[3]+red[5]+red[7];
  const float mean = s * (1.f/Dm);
  const float var  = fmaxf(s2 * (1.f/Dm) - mean*mean, 0.f);
  const float rstd = rsqrtf(var + 1e-5f);
  const float4* scp = (const float4*)sc;
  const float4* shp = (const float4*)sh;
  float4 sc0 = scp[tid*2], sc1 = scp[tid*2+1];
  float4 sh0 = shp[tid*2], sh1 = shp[tid*2+1];
  __attribute__((aligned(16))) bf16_t ob[8];
  ob[0] = (bf16_t)((v0.x-mean)*rstd*sc0.x + sh0.x);
  ob[1] = (bf16_t)((v0.y-mean)*rstd*sc0.y + sh0.y);
  ob[2] = (bf16_t)((v0.z-mean)*rstd*sc0.z + sh0.z);
  ob[3] = (bf16_t)((v0.w-mean)*rstd*sc0.w + sh0.w);
  ob[4] = (bf16_t)((v1.x-mean)*rstd*sc1.x + sh1.x);
  ob[5] = (bf16_t)((v1.y-mean)*rstd*sc1.y + sh1.y);
  ob[6] = (bf16_t)((v1.z-mean)*rstd*sc1.z + sh1.z);
  ob[7] = (bf16_t)((v1.w-mean)*rstd*sc1.w + sh1.w);
  *(uint4*)(out + (size_t)row*Dm + tid*8) = *(const uint4*)ob;
}

// ------------- weight fp32 [K][N] -> bf16 transposed [N][K] -------------
__global__ __launch_bounds__(256)
void wconv_t(const float* __restrict__ W, bf16_t* __restrict__ WT, int K, int N)
{
  __shared__ float tile[32][33];
  const int tx = threadIdx.x & 31, ty = threadIdx.x >> 5;
  const int nb = blockIdx.x * 32, kb = blockIdx.y * 32;
  #pragma unroll
  for (int p = 0; p < 4; ++p)
    tile[ty+8*p][tx] = W[(size_t)(kb+ty+8*p)*N + nb + tx];
  __syncthreads();
  #pragma unroll
  for (int p = 0; p < 4; ++p)
    WT[(size_t)(nb+ty+8*p)*K + kb + tx] = (bf16_t)tile[tx][ty+8*p];
}

__global__ void bias_concat(const float* __restrict__ bq, const float* __restrict__ bk,
                            const float* __restrict__ bv, float* __restrict__ o)
{
  int i = blockIdx.x*256 + threadIdx.x;
  o[i] = bq[i]; o[Dm+i] = bk[i]; o[2*Dm+i] = bv[i];
}

// ----- V slice of qkv [B*S][6144] -> vT [B*H][128][2048] (bf16) -----
__global__ __launch_bounds__(256)
void vtrans(const bf16_t* __restrict__ qkv, bf16_t* __restrict__ vT)
{
  __shared__ bf16_t tile[32][33];
  const int tx = threadIdx.x & 31, ty = threadIdx.x >> 5;
  const int s0 = blockIdx.x*32, d0 = blockIdx.y*32, bh = blockIdx.z;
  const int b = bh >> 4, h = bh & 15;
  const bf16_t* src = qkv + (size_t)(b*SEQ)*QW + 2*Dm + h*HDm;
  #pragma unroll
  for (int p = 0; p < 4; ++p)
    tile[ty+8*p][tx] = src[(size_t)(s0+ty+8*p)*QW + d0 + tx];
  __syncthreads();
  bf16_t* dst = vT + (size_t)bh*HDm*SEQ;
  #pragma unroll
  for (int p = 0; p < 4; ++p)
    dst[(size_t)(d0+ty+8*p)*SEQ + s0 + tx] = tile[tx][ty+8*p];
}

// ------- GEMM: C[M,N] = act(A[M,K] @ BT[N,K]^T + bias) (+resid) -------
template<bool OUT_BF16, bool GELU_, bool RESID>
__global__ __launch_bounds__(256)
void gemm_bt(const bf16_t* __restrict__ A, const bf16_t* __restrict__ BT,
             const float* __restrict__ bias, const float* __restrict__ resid,
             void* __restrict__ Cout, int Ndim, int Kdim)
{
  const int n0 = blockIdx.x * 128;
  const int m0 = blockIdx.y * 128;
  const int tid = threadIdx.x;
  const int lane = tid & 63;
  const int wid = tid >> 6;
  const int wr = wid >> 1, wc = wid & 1;
  const int lr = lane & 15, kg = lane >> 4;

  __shared__ __attribute__((aligned(16))) bf16_t As[128*32];
  __shared__ __attribute__((aligned(16))) bf16_t Bs[128*32];

  f32x4 acc[4][4] = {};

  const int ia = tid, ib = tid + 256;
  const bf16_t* gA0 = A  + (size_t)(m0 + (ia>>2))*Kdim + (ia&3)*8;
  const bf16_t* gA1 = A  + (size_t)(m0 + (ib>>2))*Kdim + (ib&3)*8;
  const bf16_t* gB0 = BT + (size_t)(n0 + (ia>>2))*Kdim + (ia&3)*8;
  const bf16_t* gB1 = BT + (size_t)(n0 + (ib>>2))*Kdim + (ib&3)*8;
  bf16_t* lA0 = As + ia*8; bf16_t* lA1 = As + ib*8;
  bf16_t* lB0 = Bs + ia*8; bf16_t* lB1 = Bs + ib*8;

  for (int k0 = 0; k0 < Kdim; k0 += 32) {
    gload_lds16(gA0 + k0, lA0);
    gload_lds16(gA1 + k0, lA1);
    gload_lds16(gB0 + k0, lB0);
    gload_lds16(gB1 + k0, lB1);
    __syncthreads();
    bf16x8 af[4], bfr[4];
    #pragma unroll
    for (int m = 0; m < 4; ++m)
      af[m] = *(const bf16x8*)(As + (wr*64 + m*16 + lr)*32 + kg*8);
    #pragma unroll
    for (int n = 0; n < 4; ++n)
      bfr[n] = *(const bf16x8*)(Bs + (wc*64 + n*16 + lr)*32 + kg*8);
    #pragma unroll
    for (int m = 0; m < 4; ++m)
      #pragma unroll
      for (int n = 0; n < 4; ++n)
        acc[m][n] = __builtin_amdgcn_mfma_f32_16x16x32_bf16(af[m], bfr[n], acc[m][n], 0, 0, 0);
    __syncthreads();
  }

  const int cr0 = m0 + wr*64 + kg*4;
  #pragma unroll
  for (int n = 0; n < 4; ++n) {
    const int col = n0 + wc*64 + n*16 + lr;
    const float bv = bias[col];
    #pragma unroll
    for (int m = 0; m < 4; ++m) {
      const int rbase = cr0 + m*16;
      #pragma unroll
      for (int j = 0; j < 4; ++j) {
        float v = acc[m][n][j] + bv;
        if constexpr (GELU_) v = 0.5f*v*(1.f + erff(v*0.70710678118f));
        size_t idx = (size_t)(rbase + j)*Ndim + col;
        if constexpr (RESID) v += resid[idx];
        if constexpr (OUT_BF16) ((bf16_t*)Cout)[idx] = (bf16_t)v;
        else ((float*)Cout)[idx] = v;
      }
    }
  }
}

// ---------------- causal flash attention v2 ----------------
// 1 wave per (bh, 32 q-rows). QBLK=32 (2 row-frags), KBLK=64.
// XCD-pinned: all blocks of one bh land on one XCD; longest tiles first.
__global__ __launch_bounds__(64, 2)
void flash_attn2(const bf16_t* __restrict__ qkv, const bf16_t* __restrict__ vT,
                 bf16_t* __restrict__ ctx)
{
  const int bid  = blockIdx.x;          // 0..2047
  const int xcd  = bid & 7;
  const int ord2 = bid >> 3;            // 0..255
  const int bh   = xcd + 8 * (ord2 & 3);   // 0..31, pinned per XCD
  const int qt   = 63 - (ord2 >> 2);       // longest first
  const int b = bh >> 4, h = bh & 15;
  const int q0 = qt * 32;
  const int lane = threadIdx.x;
  const int lr = lane & 15, kg = lane >> 4;

  // P scratch: [rt][16 rows][64 cols] bf16, XOR-swizzled (elem ^= (row&7)<<3)
  __shared__ __attribute__((aligned(16))) bf16_t Plds[2 * 16 * 64];

  bf16x8 qf[2][4];
  #pragma unroll
  for (int rt = 0; rt < 2; ++rt) {
    const bf16_t* qb = qkv + (size_t)(b*SEQ + q0 + rt*16 + lr)*QW + h*HDm;
    #pragma unroll
    for (int g = 0; g < 4; ++g)
      qf[rt][g] = *(const bf16x8*)(qb + g*32 + kg*8);
  }

  const float scl = 0.08838834764831845f * 1.44269504089f; // 1/sqrt(128)*log2(e)
  float mrow[2][4], lsum[2][4];
  f32x4 oacc[2][8];
  #pragma unroll
  for (int rt = 0; rt < 2; ++rt) {
    #pragma unroll
    for (int j = 0; j < 4; ++j) { mrow[rt][j] = -INFINITY; lsum[rt][j] = 0.f; }
    #pragma unroll
    for (int dt = 0; dt < 8; ++dt) oacc[rt][dt] = (f32x4){0.f,0.f,0.f,0.f};
  }

  const bf16_t* kbase = qkv + (size_t)(b*SEQ)*QW + Dm + h*HDm;
  const bf16_t* vbase = vT + (size_t)bh*HDm*SEQ;

  const int nsteps = (q0 + 32 + 63) >> 6;
  for (int t = 0; t < nsteps; ++t) {
    const int k0 = t * 64;
    // ---- QK^T: 32 MFMA ----
    f32x4 sa[2][4];
    #pragma unroll
    for (int rt = 0; rt < 2; ++rt)
      #pragma unroll
      for (int ct = 0; ct < 4; ++ct) sa[rt][ct] = (f32x4){0.f,0.f,0.f,0.f};
    #pragma unroll
    for (int ct = 0; ct < 4; ++ct) {
      const bf16_t* kb = kbase + (size_t)(k0 + ct*16 + lr)*QW + kg*8;
      bf16x8 kf[4];
      #pragma unroll
      for (int g = 0; g < 4; ++g) kf[g] = *(const bf16x8*)(kb + g*32);
      #pragma unroll
      for (int g = 0; g < 4; ++g) {
        sa[0][ct] = __builtin_amdgcn_mfma_f32_16x16x32_bf16(qf[0][g], kf[g], sa[0][ct], 0, 0, 0);
        sa[1][ct] = __builtin_amdgcn_mfma_f32_16x16x32_bf16(qf[1][g], kf[g], sa[1][ct], 0, 0, 0);
      }
    }
    // ---- scale + causal mask ----
    #pragma unroll
    for (int rt = 0; rt < 2; ++rt)
      #pragma unroll
      for (int ct = 0; ct < 4; ++ct)
        #pragma unroll
        for (int j = 0; j < 4; ++j) sa[rt][ct][j] *= scl;
    if (k0 + 63 > q0) {
      #pragma unroll
      for (int ct = 0; ct < 4; ++ct) {
        const int kidx = k0 + ct*16 + lr;
        #pragma unroll
        for (int rt = 0; rt < 2; ++rt)
          #pragma unroll
          for (int j = 0; j < 4; ++j) {
            const int qidx = q0 + rt*16 + kg*4 + j;
            if (kidx > qidx) sa[rt][ct][j] = -INFINITY;
          }
      }
    }
    // ---- online softmax (per row: 16-lane shfl reduce) ----
    #pragma unroll
    for (int rt = 0; rt < 2; ++rt) {
      #pragma unroll
      for (int j = 0; j < 4; ++j) {
        const int prow = kg*4 + j;
        float x0 = sa[rt][0][j], x1 = sa[rt][1][j], x2 = sa[rt][2][j], x3 = sa[rt][3][j];
        float v = fmaxf(fmaxf(x0, x1), fmaxf(x2, x3));
        v = fmaxf(v, __shfl_xor(v, 1));
        v = fmaxf(v, __shfl_xor(v, 2));
        v = fmaxf(v, __shfl_xor(v, 4));
        v = fmaxf(v, __shfl_xor(v, 8));
        const float mn = fmaxf(mrow[rt][j], v);
        const float alpha = exp2f(mrow[rt][j] - mn);
        mrow[rt][j] = mn;
        float p0 = exp2f(x0 - mn), p1 = exp2f(x1 - mn);
        float p2 = exp2f(x2 - mn), p3 = exp2f(x3 - mn);
        float s = (p0 + p1) + (p2 + p3);
        s += __shfl_xor(s, 1);
        s += __shfl_xor(s, 2);
        s += __shfl_xor(s, 4);
        s += __shfl_xor(s, 8);
        lsum[rt][j] = lsum[rt][j]*alpha + s;
        #pragma unroll
        for (int dt = 0; dt < 8; ++dt) oacc[rt][dt][j] *= alpha;
        const int base = rt*1024 + prow*64;
        const int sw = (prow & 7) << 3;
        Plds[(base + ( 0 + lr)) ^ sw] = (bf16_t)p0;
        Plds[(base + (16 + lr)) ^ sw] = (bf16_t)p1;
        Plds[(base + (32 + lr)) ^ sw] = (bf16_t)p2;
        Plds[(base + (48 + lr)) ^ sw] = (bf16_t)p3;
      }
    }
    __syncthreads();   // single-wave block: cheap; orders P write->read
    // ---- PV: P[32x64] @ V[64x128] ----
    bf16x8 pf[2][2];
    #pragma unroll
    for (int rt = 0; rt < 2; ++rt) {
      const int sw = (lr & 7) << 3;
      pf[rt][0] = *(const bf16x8*)(Plds + ((rt*1024 + lr*64 +      kg*8) ^ sw));
      pf[rt][1] = *(const bf16x8*)(Plds + ((rt*1024 + lr*64 + 32 + kg*8) ^ sw));
    }
    #pragma unroll
    for (int dt = 0; dt < 8; ++dt) {
      #pragma unroll
      for (int kc = 0; kc < 2; ++kc) {
        bf16x8 vf = *(const bf16x8*)(vbase + (size_t)(dt*16 + lr)*SEQ + k0 + kc*32 + kg*8);
        oacc[0][dt] = __builtin_amdgcn_mfma_f32_16x16x32_bf16(pf[0][kc], vf, oacc[0][dt], 0, 0, 0);
        oacc[1][dt] = __builtin_amdgcn_mfma_f32_16x16x32_bf16(pf[1][kc], vf, oacc[1][dt], 0, 0, 0);
      }
    }
  }

  #pragma unroll
  for (int rt = 0; rt < 2; ++rt) {
    bf16_t* cb = ctx + (size_t)(b*SEQ + q0 + rt*16 + kg*4)*Dm + h*HDm;
    #pragma unroll
    for (int j = 0; j < 4; ++j) {
      const float inv = 1.f / lsum[rt][j];
      #pragma unroll
      for (int dt = 0; dt < 8; ++dt)
        cb[(size_t)j*Dm + dt*16 + lr] = (bf16_t)(oacc[rt][dt][j] * inv);
    }
  }
}

} // namespace

extern "C" void kernel_launch(void* const* d_in, const int* in_sizes, int n_in,
                              void* d_out, int out_size, void* d_ws, size_t ws_size,
                              hipStream_t stream)
{
  const float* x   = (const float*)d_in[0];
  const float* g1  = (const float*)d_in[1];
  const float* s1  = (const float*)d_in[2];
  const float* wq  = (const float*)d_in[3];
  const float* bq  = (const float*)d_in[4];
  const float* wk  = (const float*)d_in[5];
  const float* bk  = (const float*)d_in[6];
  const float* wv  = (const float*)d_in[7];
  const float* bv  = (const float*)d_in[8];
  const float* wo  = (const float*)d_in[9];
  const float* bo  = (const float*)d_in[10];
  const float* g2  = (const float*)d_in[11];
  const float* s2  = (const float*)d_in[12];
  const float* w1  = (const float*)d_in[13];
  const float* b1  = (const float*)d_in[14];
  const float* w2  = (const float*)d_in[15];
  const float* b2  = (const float*)d_in[16];
  float* out = (float*)d_out;

  char* p = (char*)d_ws;
  bf16_t* wqkvT = (bf16_t*)p;  p += (size_t)QW*Dm*2;
  bf16_t* woT   = (bf16_t*)p;  p += (size_t)Dm*Dm*2;
  bf16_t* w1T   = (bf16_t*)p;  p += (size_t)FFm*Dm*2;
  bf16_t* w2T   = (bf16_t*)p;  p += (size_t)Dm*FFm*2;
  float*  bqkv  = (float*)p;   p += (size_t)QW*4;
  bf16_t* hbuf  = (bf16_t*)p;  p += (size_t)MR*Dm*2;
  bf16_t* qkv   = (bf16_t*)p;  p += (size_t)MR*QW*2;
  bf16_t* vTb   = (bf16_t*)p;  p += (size_t)32*HDm*SEQ*2;
  bf16_t* ctx   = (bf16_t*)p;  p += (size_t)MR*Dm*2;
  float*  x1    = (float*)p;   p += (size_t)MR*Dm*4;
  bf16_t* ffn1  = qkv;  // reuse qkv+vT+ctx region

  wconv_t<<<dim3(Dm/32, Dm/32), 256, 0, stream>>>(wq, wqkvT, Dm, Dm);
  wconv_t<<<dim3(Dm/32, Dm/32), 256, 0, stream>>>(wk, wqkvT + (size_t)Dm*Dm, Dm, Dm);
  wconv_t<<<dim3(Dm/32, Dm/32), 256, 0, stream>>>(wv, wqkvT + (size_t)2*Dm*Dm, Dm, Dm);
  wconv_t<<<dim3(Dm/32, Dm/32), 256, 0, stream>>>(wo, woT, Dm, Dm);
  wconv_t<<<dim3(FFm/32, Dm/32), 256, 0, stream>>>(w1, w1T, Dm, FFm);
  wconv_t<<<dim3(Dm/32, FFm/32), 256, 0, stream>>>(w2, w2T, FFm, Dm);
  bias_concat<<<dim3(Dm/256), 256, 0, stream>>>(bq, bk, bv, bqkv);

  ln_kernel<<<dim3(MR), 256, 0, stream>>>(x, g1, s1, hbuf);
  gemm_bt<true,false,false><<<dim3(QW/128, MR/128), 256, 0, stream>>>(
      hbuf, wqkvT, bqkv, nullptr, qkv, QW, Dm);
  vtrans<<<dim3(SEQ/32, HDm/32, 32), 256, 0, stream>>>(qkv, vTb);
  flash_attn2<<<dim3(2048), 64, 0, stream>>>(qkv, vTb, ctx);
  gemm_bt<false,false,true><<<dim3(Dm/128, MR/128), 256, 0, stream>>>(
      ctx, woT, bo, x, x1, Dm, Dm);
  ln_kernel<<<dim3(MR), 256, 0, stream>>>(x1, g2, s2, hbuf);
  gemm_bt<true,true,false><<<dim3(FFm/128, MR/128), 256, 0, stream>>>(
      hbuf, w1T, b1, nullptr, ffn1, FFm, Dm);
  gemm_bt<false,false,true><<<dim3(Dm/128, MR/128), 256, 0, stream>>>(
      ffn1, w2T, b2, x1, out, Dm, FFm);
}

// Round 3
// 894.995 us; speedup vs baseline: 1.1743x; 1.1094x over previous
//
#include <hip/hip_runtime.h>
#include <hip/hip_bf16.h>
#include <math.h>

namespace {

constexpr int Dm  = 2048;
constexpr int FFm = 8192;
constexpr int SEQ = 2048;
constexpr int HDm = 128;
constexpr int MR  = 4096;     // B*S
constexpr int QW  = 3 * Dm;   // 6144

typedef __bf16 bf16_t;
typedef __bf16 bf16x8 __attribute__((ext_vector_type(8)));
typedef float  f32x4  __attribute__((ext_vector_type(4)));

typedef __attribute__((address_space(1))) const void as1_void;
typedef __attribute__((address_space(3))) void as3_void;

__device__ __forceinline__ void gload_lds16(const void* g, void* l) {
  __builtin_amdgcn_global_load_lds((as1_void*)g, (as3_void*)l, 16, 0, 0);
}

// ---------------- LayerNorm: fp32 in -> bf16 out ----------------
__global__ __launch_bounds__(256)
void ln_kernel(const float* __restrict__ x, const float* __restrict__ sc,
               const float* __restrict__ sh, bf16_t* __restrict__ out)
{
  const int row = blockIdx.x;
  const int tid = threadIdx.x;
  const float4* xr = (const float4*)(x + (size_t)row * Dm);
  float4 v0 = xr[tid*2], v1 = xr[tid*2+1];
  float s  = v0.x+v0.y+v0.z+v0.w + v1.x+v1.y+v1.z+v1.w;
  float s2 = v0.x*v0.x+v0.y*v0.y+v0.z*v0.z+v0.w*v0.w
           + v1.x*v1.x+v1.y*v1.y+v1.z*v1.z+v1.w*v1.w;
  #pragma unroll
  for (int off = 32; off; off >>= 1) { s += __shfl_xor(s, off); s2 += __shfl_xor(s2, off); }
  __shared__ float red[8];
  if ((tid & 63) == 0) { red[(tid>>6)*2] = s; red[(tid>>6)*2+1] = s2; }
  __syncthreads();
  s  = red[0]+red[2]+red[4]+red[6];
  s2 = red[1]+red[3]+red[5]+red[7];
  const float mean = s * (1.f/Dm);
  const float var  = fmaxf(s2 * (1.f/Dm) - mean*mean, 0.f);
  const float rstd = rsqrtf(var + 1e-5f);
  const float4* scp = (const float4*)sc;
  const float4* shp = (const float4*)sh;
  float4 sc0 = scp[tid*2], sc1 = scp[tid*2+1];
  float4 sh0 = shp[tid*2], sh1 = shp[tid*2+1];
  __attribute__((aligned(16))) bf16_t ob[8];
  ob[0] = (bf16_t)((v0.x-mean)*rstd*sc0.x + sh0.x);
  ob[1] = (bf16_t)((v0.y-mean)*rstd*sc0.y + sh0.y);
  ob[2] = (bf16_t)((v0.z-mean)*rstd*sc0.z + sh0.z);
  ob[3] = (bf16_t)((v0.w-mean)*rstd*sc0.w + sh0.w);
  ob[4] = (bf16_t)((v1.x-mean)*rstd*sc1.x + sh1.x);
  ob[5] = (bf16_t)((v1.y-mean)*rstd*sc1.y + sh1.y);
  ob[6] = (bf16_t)((v1.z-mean)*rstd*sc1.z + sh1.z);
  ob[7] = (bf16_t)((v1.w-mean)*rstd*sc1.w + sh1.w);
  *(uint4*)(out + (size_t)row*Dm + tid*8) = *(const uint4*)ob;
}

// ------------- weight fp32 [K][N] -> bf16 transposed [N][K] -------------
__global__ __launch_bounds__(256)
void wconv_t(const float* __restrict__ W, bf16_t* __restrict__ WT, int K, int N)
{
  __shared__ float tile[32][33];
  const int tx = threadIdx.x & 31, ty = threadIdx.x >> 5;
  const int nb = blockIdx.x * 32, kb = blockIdx.y * 32;
  #pragma unroll
  for (int p = 0; p < 4; ++p)
    tile[ty+8*p][tx] = W[(size_t)(kb+ty+8*p)*N + nb + tx];
  __syncthreads();
  #pragma unroll
  for (int p = 0; p < 4; ++p)
    WT[(size_t)(nb+ty+8*p)*K + kb + tx] = (bf16_t)tile[tx][ty+8*p];
}

__global__ void bias_concat(const float* __restrict__ bq, const float* __restrict__ bk,
                            const float* __restrict__ bv, float* __restrict__ o)
{
  int i = blockIdx.x*256 + threadIdx.x;
  o[i] = bq[i]; o[Dm+i] = bk[i]; o[2*Dm+i] = bv[i];
}

// ----- V slice of qkv [B*S][6144] -> vT [B*H][128][2048] (bf16) -----
__global__ __launch_bounds__(256)
void vtrans(const bf16_t* __restrict__ qkv, bf16_t* __restrict__ vT)
{
  __shared__ bf16_t tile[32][33];
  const int tx = threadIdx.x & 31, ty = threadIdx.x >> 5;
  const int s0 = blockIdx.x*32, d0 = blockIdx.y*32, bh = blockIdx.z;
  const int b = bh >> 4, h = bh & 15;
  const bf16_t* src = qkv + (size_t)(b*SEQ)*QW + 2*Dm + h*HDm;
  #pragma unroll
  for (int p = 0; p < 4; ++p)
    tile[ty+8*p][tx] = src[(size_t)(s0+ty+8*p)*QW + d0 + tx];
  __syncthreads();
  bf16_t* dst = vT + (size_t)bh*HDm*SEQ;
  #pragma unroll
  for (int p = 0; p < 4; ++p)
    dst[(size_t)(d0+ty+8*p)*SEQ + s0 + tx] = tile[tx][ty+8*p];
}

// ------- GEMM: C[M,N] = act(A[M,K] @ BT[N,K]^T + bias) (+resid) -------
// 1D grid with XCD-aware swizzle (T1); nwg must be %8==0.
template<bool OUT_BF16, bool GELU_, bool RESID>
__global__ __launch_bounds__(256)
void gemm_bt(const bf16_t* __restrict__ A, const bf16_t* __restrict__ BT,
             const float* __restrict__ bias, const float* __restrict__ resid,
             void* __restrict__ Cout, int Ndim, int Kdim, int gx)
{
  const int nwg = gridDim.x;
  int flat = blockIdx.x;
  flat = (flat & 7) * (nwg >> 3) + (flat >> 3);   // XCD-contiguous chunks
  const int n0 = (flat % gx) * 128;
  const int m0 = (flat / gx) * 128;
  const int tid = threadIdx.x;
  const int lane = tid & 63;
  const int wid = tid >> 6;
  const int wr = wid >> 1, wc = wid & 1;
  const int lr = lane & 15, kg = lane >> 4;

  __shared__ __attribute__((aligned(16))) bf16_t As[128*32];
  __shared__ __attribute__((aligned(16))) bf16_t Bs[128*32];

  f32x4 acc[4][4] = {};

  const int ia = tid, ib = tid + 256;
  const bf16_t* gA0 = A  + (size_t)(m0 + (ia>>2))*Kdim + (ia&3)*8;
  const bf16_t* gA1 = A  + (size_t)(m0 + (ib>>2))*Kdim + (ib&3)*8;
  const bf16_t* gB0 = BT + (size_t)(n0 + (ia>>2))*Kdim + (ia&3)*8;
  const bf16_t* gB1 = BT + (size_t)(n0 + (ib>>2))*Kdim + (ib&3)*8;
  bf16_t* lA0 = As + ia*8; bf16_t* lA1 = As + ib*8;
  bf16_t* lB0 = Bs + ia*8; bf16_t* lB1 = Bs + ib*8;

  for (int k0 = 0; k0 < Kdim; k0 += 32) {
    gload_lds16(gA0 + k0, lA0);
    gload_lds16(gA1 + k0, lA1);
    gload_lds16(gB0 + k0, lB0);
    gload_lds16(gB1 + k0, lB1);
    __syncthreads();
    bf16x8 af[4], bfr[4];
    #pragma unroll
    for (int m = 0; m < 4; ++m)
      af[m] = *(const bf16x8*)(As + (wr*64 + m*16 + lr)*32 + kg*8);
    #pragma unroll
    for (int n = 0; n < 4; ++n)
      bfr[n] = *(const bf16x8*)(Bs + (wc*64 + n*16 + lr)*32 + kg*8);
    #pragma unroll
    for (int m = 0; m < 4; ++m)
      #pragma unroll
      for (int n = 0; n < 4; ++n)
        acc[m][n] = __builtin_amdgcn_mfma_f32_16x16x32_bf16(af[m], bfr[n], acc[m][n], 0, 0, 0);
    __syncthreads();
  }

  const int cr0 = m0 + wr*64 + kg*4;
  #pragma unroll
  for (int n = 0; n < 4; ++n) {
    const int col = n0 + wc*64 + n*16 + lr;
    const float bv = bias[col];
    #pragma unroll
    for (int m = 0; m < 4; ++m) {
      const int rbase = cr0 + m*16;
      #pragma unroll
      for (int j = 0; j < 4; ++j) {
        float v = acc[m][n][j] + bv;
        if constexpr (GELU_) v = 0.5f*v*(1.f + erff(v*0.70710678118f));
        size_t idx = (size_t)(rbase + j)*Ndim + col;
        if constexpr (RESID) v += resid[idx];
        if constexpr (OUT_BF16) ((bf16_t*)Cout)[idx] = (bf16_t)v;
        else ((float*)Cout)[idx] = v;
      }
    }
  }
}

// ---------------- causal flash attention v3 ----------------
// 8 waves/block, wave w owns 32 q-rows; block = 256 q-rows. KVBLK=64.
// K and V^T staged in LDS via global_load_lds with XOR slot swizzle.
__global__ __launch_bounds__(512, 2)
void flash_attn3(const bf16_t* __restrict__ qkv, const bf16_t* __restrict__ vT,
                 bf16_t* __restrict__ ctx)
{
  const int bid = blockIdx.x;                  // 0..255
  const int bh  = (bid & 7) + 8 * ((bid >> 3) & 3);  // XCD-pinned head
  const int qi  = 7 - (bid >> 5);              // longest q-tiles first
  const int b = bh >> 4, h = bh & 15;
  const int Q0 = qi * 256;
  const int tid = threadIdx.x;
  const int lane = tid & 63;
  const int w = tid >> 6;
  const int lr = lane & 15, kg = lane >> 4;
  const int q0w = Q0 + w * 32;

  // K tile: [64 key][128 d], 16 slots(16B)/row, slot ^= (row&7)
  // V tile: [128 d][64 key],  8 slots(16B)/row, slot ^= (row&7)
  __shared__ __attribute__((aligned(16))) bf16_t Ks[64*128];
  __shared__ __attribute__((aligned(16))) bf16_t Vs[128*64];
  __shared__ __attribute__((aligned(16))) bf16_t Plds[8*2048];

  const bf16_t* kbase = qkv + (size_t)(b*SEQ)*QW + Dm + h*HDm;
  const bf16_t* vbase = vT + (size_t)bh*HDm*SEQ;

  bf16x8 qf[2][4];
  #pragma unroll
  for (int rt = 0; rt < 2; ++rt) {
    const bf16_t* qb = qkv + (size_t)(b*SEQ + q0w + rt*16 + lr)*QW + h*HDm;
    #pragma unroll
    for (int g = 0; g < 4; ++g)
      qf[rt][g] = *(const bf16x8*)(qb + g*32 + kg*8);
  }

  const float scl = 0.08838834764831845f * 1.44269504089f; // 1/sqrt(128)*log2(e)
  float mrow[2][4], lsum[2][4];
  f32x4 oacc[2][8];
  #pragma unroll
  for (int rt = 0; rt < 2; ++rt) {
    #pragma unroll
    for (int j = 0; j < 4; ++j) { mrow[rt][j] = -INFINITY; lsum[rt][j] = 0.f; }
    #pragma unroll
    for (int dt = 0; dt < 8; ++dt) oacc[rt][dt] = (f32x4){0.f,0.f,0.f,0.f};
  }

  auto stage = [&](int k0) {
    #pragma unroll
    for (int i = 0; i < 2; ++i) {
      const int s = tid + i*512;                 // K slot
      const int row = s >> 4, sl = s & 15;
      gload_lds16(kbase + (size_t)(k0 + row)*QW + (sl ^ (row & 7))*8, Ks + s*8);
    }
    #pragma unroll
    for (int i = 0; i < 2; ++i) {
      const int s = tid + i*512;                 // V slot
      const int row = s >> 3, sl = s & 7;
      gload_lds16(vbase + (size_t)row*SEQ + k0 + (sl ^ (row & 7))*8, Vs + s*8);
    }
  };

  const int nsteps = (Q0 + 256) >> 6;
  stage(0);
  for (int t = 0; t < nsteps; ++t) {
    const int k0 = t * 64;
    __syncthreads();                             // staging complete
    if (k0 < q0w + 32) {
      // ---- QK^T from Ks ----
      f32x4 sa[2][4];
      #pragma unroll
      for (int rt = 0; rt < 2; ++rt)
        #pragma unroll
        for (int ct = 0; ct < 4; ++ct) sa[rt][ct] = (f32x4){0.f,0.f,0.f,0.f};
      #pragma unroll
      for (int ct = 0; ct < 4; ++ct) {
        const int krow = ct*16 + lr;
        #pragma unroll
        for (int g = 0; g < 4; ++g) {
          bf16x8 kf = *(const bf16x8*)(Ks + krow*128 + ((4*g + kg) ^ (krow & 7))*8);
          sa[0][ct] = __builtin_amdgcn_mfma_f32_16x16x32_bf16(qf[0][g], kf, sa[0][ct], 0, 0, 0);
          sa[1][ct] = __builtin_amdgcn_mfma_f32_16x16x32_bf16(qf[1][g], kf, sa[1][ct], 0, 0, 0);
        }
      }
      // ---- scale + causal mask ----
      #pragma unroll
      for (int rt = 0; rt < 2; ++rt)
        #pragma unroll
        for (int ct = 0; ct < 4; ++ct)
          #pragma unroll
          for (int j = 0; j < 4; ++j) sa[rt][ct][j] *= scl;
      if (k0 + 63 > q0w) {
        #pragma unroll
        for (int ct = 0; ct < 4; ++ct) {
          const int kidx = k0 + ct*16 + lr;
          #pragma unroll
          for (int rt = 0; rt < 2; ++rt)
            #pragma unroll
            for (int j = 0; j < 4; ++j) {
              const int qidx = q0w + rt*16 + kg*4 + j;
              if (kidx > qidx) sa[rt][ct][j] = -INFINITY;
            }
        }
      }
      // ---- online softmax ----
      #pragma unroll
      for (int rt = 0; rt < 2; ++rt) {
        #pragma unroll
        for (int j = 0; j < 4; ++j) {
          const int prow = kg*4 + j;
          float x0 = sa[rt][0][j], x1 = sa[rt][1][j], x2 = sa[rt][2][j], x3 = sa[rt][3][j];
          float v = fmaxf(fmaxf(x0, x1), fmaxf(x2, x3));
          v = fmaxf(v, __shfl_xor(v, 1));
          v = fmaxf(v, __shfl_xor(v, 2));
          v = fmaxf(v, __shfl_xor(v, 4));
          v = fmaxf(v, __shfl_xor(v, 8));
          const float mn = fmaxf(mrow[rt][j], v);
          const float alpha = exp2f(mrow[rt][j] - mn);
          mrow[rt][j] = mn;
          float p0 = exp2f(x0 - mn), p1 = exp2f(x1 - mn);
          float p2 = exp2f(x2 - mn), p3 = exp2f(x3 - mn);
          float s = (p0 + p1) + (p2 + p3);
          s += __shfl_xor(s, 1);
          s += __shfl_xor(s, 2);
          s += __shfl_xor(s, 4);
          s += __shfl_xor(s, 8);
          lsum[rt][j] = lsum[rt][j]*alpha + s;
          #pragma unroll
          for (int dt = 0; dt < 8; ++dt) oacc[rt][dt][j] *= alpha;
          const int base = w*2048 + rt*1024 + prow*64;
          const int sw = (prow & 7) << 3;
          Plds[(base + ( 0 + lr)) ^ sw] = (bf16_t)p0;
          Plds[(base + (16 + lr)) ^ sw] = (bf16_t)p1;
          Plds[(base + (32 + lr)) ^ sw] = (bf16_t)p2;
          Plds[(base + (48 + lr)) ^ sw] = (bf16_t)p3;
        }
      }
      // ---- PV from Vs ----
      bf16x8 pf[2][2];
      {
        const int sw = (lr & 7) << 3;
        #pragma unroll
        for (int rt = 0; rt < 2; ++rt) {
          pf[rt][0] = *(const bf16x8*)(Plds + ((w*2048 + rt*1024 + lr*64 +      kg*8) ^ sw));
          pf[rt][1] = *(const bf16x8*)(Plds + ((w*2048 + rt*1024 + lr*64 + 32 + kg*8) ^ sw));
        }
      }
      #pragma unroll
      for (int dt = 0; dt < 8; ++dt) {
        const int vrow = dt*16 + lr;
        #pragma unroll
        for (int kc = 0; kc < 2; ++kc) {
          bf16x8 vf = *(const bf16x8*)(Vs + vrow*64 + ((4*kc + kg) ^ (vrow & 7))*8);
          oacc[0][dt] = __builtin_amdgcn_mfma_f32_16x16x32_bf16(pf[0][kc], vf, oacc[0][dt], 0, 0, 0);
          oacc[1][dt] = __builtin_amdgcn_mfma_f32_16x16x32_bf16(pf[1][kc], vf, oacc[1][dt], 0, 0, 0);
        }
      }
    }
    __syncthreads();                             // all reads of Ks/Vs done
    if (t + 1 < nsteps) stage((t + 1) * 64);
  }

  #pragma unroll
  for (int rt = 0; rt < 2; ++rt) {
    bf16_t* cb = ctx + (size_t)(b*SEQ + q0w + rt*16 + kg*4)*Dm + h*HDm;
    #pragma unroll
    for (int j = 0; j < 4; ++j) {
      const float inv = 1.f / lsum[rt][j];
      #pragma unroll
      for (int dt = 0; dt < 8; ++dt)
        cb[(size_t)j*Dm + dt*16 + lr] = (bf16_t)(oacc[rt][dt][j] * inv);
    }
  }
}

} // namespace

extern "C" void kernel_launch(void* const* d_in, const int* in_sizes, int n_in,
                              void* d_out, int out_size, void* d_ws, size_t ws_size,
                              hipStream_t stream)
{
  const float* x   = (const float*)d_in[0];
  const float* g1  = (const float*)d_in[1];
  const float* s1  = (const float*)d_in[2];
  const float* wq  = (const float*)d_in[3];
  const float* bq  = (const float*)d_in[4];
  const float* wk  = (const float*)d_in[5];
  const float* bk  = (const float*)d_in[6];
  const float* wv  = (const float*)d_in[7];
  const float* bv  = (const float*)d_in[8];
  const float* wo  = (const float*)d_in[9];
  const float* bo  = (const float*)d_in[10];
  const float* g2  = (const float*)d_in[11];
  const float* s2  = (const float*)d_in[12];
  const float* w1  = (const float*)d_in[13];
  const float* b1  = (const float*)d_in[14];
  const float* w2  = (const float*)d_in[15];
  const float* b2  = (const float*)d_in[16];
  float* out = (float*)d_out;

  char* p = (char*)d_ws;
  bf16_t* wqkvT = (bf16_t*)p;  p += (size_t)QW*Dm*2;
  bf16_t* woT   = (bf16_t*)p;  p += (size_t)Dm*Dm*2;
  bf16_t* w1T   = (bf16_t*)p;  p += (size_t)FFm*Dm*2;
  bf16_t* w2T   = (bf16_t*)p;  p += (size_t)Dm*FFm*2;
  float*  bqkv  = (float*)p;   p += (size_t)QW*4;
  bf16_t* hbuf  = (bf16_t*)p;  p += (size_t)MR*Dm*2;
  bf16_t* qkv   = (bf16_t*)p;  p += (size_t)MR*QW*2;
  bf16_t* vTb   = (bf16_t*)p;  p += (size_t)32*HDm*SEQ*2;
  bf16_t* ctx   = (bf16_t*)p;  p += (size_t)MR*Dm*2;
  float*  x1    = (float*)p;   p += (size_t)MR*Dm*4;
  bf16_t* ffn1  = qkv;  // reuse qkv+vT+ctx region

  wconv_t<<<dim3(Dm/32, Dm/32), 256, 0, stream>>>(wq, wqkvT, Dm, Dm);
  wconv_t<<<dim3(Dm/32, Dm/32), 256, 0, stream>>>(wk, wqkvT + (size_t)Dm*Dm, Dm, Dm);
  wconv_t<<<dim3(Dm/32, Dm/32), 256, 0, stream>>>(wv, wqkvT + (size_t)2*Dm*Dm, Dm, Dm);
  wconv_t<<<dim3(Dm/32, Dm/32), 256, 0, stream>>>(wo, woT, Dm, Dm);
  wconv_t<<<dim3(FFm/32, Dm/32), 256, 0, stream>>>(w1, w1T, Dm, FFm);
  wconv_t<<<dim3(Dm/32, FFm/32), 256, 0, stream>>>(w2, w2T, FFm, Dm);
  bias_concat<<<dim3(Dm/256), 256, 0, stream>>>(bq, bk, bv, bqkv);

  ln_kernel<<<dim3(MR), 256, 0, stream>>>(x, g1, s1, hbuf);
  gemm_bt<true,false,false><<<dim3((QW/128)*(MR/128)), 256, 0, stream>>>(
      hbuf, wqkvT, bqkv, nullptr, qkv, QW, Dm, QW/128);
  vtrans<<<dim3(SEQ/32, HDm/32, 32), 256, 0, stream>>>(qkv, vTb);
  flash_attn3<<<dim3(256), 512, 0, stream>>>(qkv, vTb, ctx);
  gemm_bt<false,false,true><<<dim3((Dm/128)*(MR/128)), 256, 0, stream>>>(
      ctx, woT, bo, x, x1, Dm, Dm, Dm/128);
  ln_kernel<<<dim3(MR), 256, 0, stream>>>(x1, g2, s2, hbuf);
  gemm_bt<true,true,false><<<dim3((FFm/128)*(MR/128)), 256, 0, stream>>>(
      hbuf, w1T, b1, nullptr, ffn1, FFm, Dm, FFm/128);
  gemm_bt<false,false,true><<<dim3((Dm/128)*(MR/128)), 256, 0, stream>>>(
      ffn1, w2T, b2, x1, out, Dm, FFm, Dm/128);
}